// Round 5
// baseline (504.746 us; speedup 1.0000x reference)
//
#include <hip/hip_runtime.h>

#define B_   8
#define S_   512
#define V_   32000
#define CTX_ 8
#define NC_  512
#define D_   256
#define NH_  4
#define L_   4
#define FF_  512
#define HD_  64
#define BS_  4096   // B_*S_

#define FG_F32   1   // write Cf f32 [row][TN]
#define FG_BF16  2   // write Cb bf16 [row][TN]
#define FG_RELU  4
#define FG_POS   8
#define FG_NT    16
#define FG_QKV   32  // route to q/k/vT head layouts (TN=768)
#define FG_LNA   64  // A-side: layernorm(x f32) during staging (K must be 256, BM 64)
#define FG_STATS 128 // epilogue: write per-row partial (sum, sumsq) to stats_out

typedef __attribute__((ext_vector_type(8))) short bf16x8;
typedef __attribute__((ext_vector_type(4))) float f32x4;

__device__ inline void gload16(const void* g, void* lds) {
    __builtin_amdgcn_global_load_lds(
        (const __attribute__((address_space(1))) void*)g,
        (__attribute__((address_space(3))) void*)lds, 16, 0, 0);
}

__device__ inline ushort f2b(float f) {   // f32 -> bf16 RNE
    union { float f; unsigned u; } v; v.f = f;
    unsigned u = v.u;
    unsigned r = u + 0x7fffu + ((u >> 16) & 1u);
    return (ushort)(r >> 16);
}

// ---------------------------------------------------------------------------
// Embedding: bf16 scores [BS][NC], pre-scaled by 1/8 (window mean)
// ---------------------------------------------------------------------------
__global__ __launch_bounds__(256) void embed_bf16_kernel(
    const int* __restrict__ tok, const float* __restrict__ table,
    ushort* __restrict__ scores)
{
    int bs = blockIdx.x;
    int b = bs >> 9, s = bs & 511;
    int j = threadIdx.x;
    float a0 = 0.f, a1 = 0.f;
    #pragma unroll
    for (int c = 0; c < CTX_; ++c) {
        int pos = s + c - (CTX_ - 1);
        int t = (pos < 0) ? 0 : tok[b * S_ + pos];
        const float* row = table + (size_t)t * NC_;
        a0 += row[j];
        a1 += row[j + 256];
    }
    scores[(size_t)bs * NC_ + j]       = f2b(a0 * 0.125f);
    scores[(size_t)bs * NC_ + j + 256] = f2b(a1 * 0.125f);
}

// ---------------------------------------------------------------------------
// Setup: cc[l] = ca_bv[l] @ ca_Wo[l] + ca_bo[l] (exact CA reduction)
//        qkvb[l][768] = concat(bq, bk, bv)
// grid L_, block 1024 (threads 0-255: cc, 256-1023: pack)
// ---------------------------------------------------------------------------
__global__ __launch_bounds__(1024) void setup_kernel(
    const float* __restrict__ ca_bv, const float* __restrict__ ca_Wo,
    const float* __restrict__ ca_bo, float* __restrict__ cc,
    const float* __restrict__ bq, const float* __restrict__ bk,
    const float* __restrict__ bv, float* __restrict__ qkvb)
{
    int l = blockIdx.x, t = threadIdx.x;
    if (t < 256) {
        const float* w = ca_Wo + (size_t)l * D_ * D_;
        const float* b = ca_bv + l * D_;
        float acc = 0.f;
        for (int d = 0; d < D_; ++d) acc += b[d] * w[(size_t)d * D_ + t];
        cc[l * D_ + t] = acc + ca_bo[l * D_ + t];
    } else {
        int u = t - 256;
        int which = u >> 8, c = u & 255;
        const float* src = which == 0 ? bq : which == 1 ? bk : bv;
        qkvb[l * 768 + u] = src[l * 256 + c];
    }
}

// ---------------------------------------------------------------------------
// All weight transposes in ONE launch: W[K][N] f32 -> Wb[N][K] bf16,
// 32x32 tiles, flat job id. Grid 10176, block (32,8).
// ---------------------------------------------------------------------------
__global__ void transpose_all_kernel(
    const float* __restrict__ proj_W, const float* __restrict__ Wq,
    const float* __restrict__ Wk, const float* __restrict__ Wv,
    const float* __restrict__ Wo, const float* __restrict__ W1,
    const float* __restrict__ W2, const float* __restrict__ outW,
    ushort* __restrict__ pjWb, ushort* __restrict__ WqkvB,
    ushort* __restrict__ WoB, ushort* __restrict__ ff1B,
    ushort* __restrict__ ff2B, ushort* __restrict__ Wb)
{
    int id = blockIdx.x;
    const float* src; ushort* dst; int K, N, lt;
    if (id < 128)       { src = proj_W; dst = pjWb; K = 512; N = 256; lt = id; }
    else if (id < 896)  { lt = id - 128; int z = lt >> 6; lt &= 63;
                          int which = z / L_, l = z % L_;
                          src = (which == 0 ? Wq : which == 1 ? Wk : Wv) + (size_t)l * 65536;
                          dst = WqkvB + ((size_t)l * 768 + which * 256) * 256;
                          K = 256; N = 256; }
    else if (id < 1152) { lt = id - 896; int l = lt >> 6; lt &= 63;
                          src = Wo + (size_t)l * 65536; dst = WoB + (size_t)l * 65536;
                          K = 256; N = 256; }
    else if (id < 1664) { lt = id - 1152; int l = lt >> 7; lt &= 127;
                          src = W1 + (size_t)l * 131072; dst = ff1B + (size_t)l * 131072;
                          K = 256; N = 512; }
    else if (id < 2176) { lt = id - 1664; int l = lt >> 7; lt &= 127;
                          src = W2 + (size_t)l * 131072; dst = ff2B + (size_t)l * 131072;
                          K = 512; N = 256; }
    else                { lt = id - 2176; src = outW; dst = Wb; K = 256; N = 32000; }
    int ntc = N >> 5;
    int n0 = (lt % ntc) * 32, k0 = (lt / ntc) * 32;
    __shared__ float tile[32][33];
    for (int i = threadIdx.y; i < 32; i += 8)
        tile[i][threadIdx.x] = src[(size_t)(k0 + i) * N + n0 + threadIdx.x];
    __syncthreads();
    for (int i = threadIdx.y; i < 32; i += 8)
        dst[(size_t)(n0 + i) * K + k0 + threadIdx.x] = f2b(tile[threadIdx.x][i]);
}

// ---------------------------------------------------------------------------
// Templated bf16 MFMA GEMM.  A[4096][K] bf16 (or LN(x f32) when FG_LNA),
// Bt[TN][K] bf16.  4 waves (2x2).  BK=64.  LDS XOR-swizzled (T2, rule #21).
// FG_STATS: epilogue writes per-row partial (sum,sumsq) -> stats_out[8][4096].
// FG_LNA:   A-staging = layernorm of Ax f32 using stats_in + lnS/lnB.
// ---------------------------------------------------------------------------
template<int BM, int BN, int K, int TN, int FLAGS>
__global__ __launch_bounds__(256) void gemm_t(
    const ushort* __restrict__ A, const float* __restrict__ Ax,
    const ushort* __restrict__ Bt,
    const float* __restrict__ bias, const float* __restrict__ extra,
    const float* __restrict__ resid, const float* __restrict__ pos,
    const float* __restrict__ lnS, const float* __restrict__ lnB,
    const float2* __restrict__ stats_in, float2* __restrict__ stats_out,
    float* __restrict__ Cf, ushort* __restrict__ Cb)
{
    constexpr int WM = BM / 32;
    constexpr int WN = BN / 32;
    constexpr int MT = 4096 / BM;
    constexpr int NWG = MT * (TN / BN);
    __shared__ ushort As[BM * 64];
    __shared__ ushort Bs[BN * 64];
    int bid = blockIdx.x;
    int swz = bid;
    if constexpr ((NWG & 7) == 0) {
        constexpr int cpx = NWG >> 3;
        swz = (bid & 7) * cpx + (bid >> 3);
    }
    int mt = swz % MT, nt = swz / MT;
    int row0 = mt * BM, col0 = nt * BN;
    int t = threadIdx.x, w = t >> 6, lane = t & 63;
    int wr = w >> 1, wc = w & 1;
    int srow = lane >> 3, slot = lane & 7;
    int gcol = (slot ^ srow) * 8;          // inverse-swizzled global col

    // LNA per-thread row stats (row = t>>2, col-quarter = t&3)
    int arow_ = t >> 2, acq_ = t & 3;
    float mean_ = 0.f, rstd_ = 0.f;
    if constexpr (FLAGS & FG_LNA) {
        float sum = 0.f, sq = 0.f;
        #pragma unroll
        for (int p = 0; p < 8; ++p) {
            float2 s = stats_in[p * 4096 + row0 + arow_];
            sum += s.x; sq += s.y;
        }
        mean_ = sum * (1.f / 256.f);
        rstd_ = rsqrtf(sq * (1.f / 256.f) - mean_ * mean_ + 1e-5f);
    }

    f32x4 acc[WM][WN] = {};
    int sl = lane >> 4;
    int rA0 = wr * (BM / 2) + (lane & 15);
    int rB0 = wc * (BN / 2) + (lane & 15);

    #pragma unroll
    for (int k0 = 0; k0 < K; k0 += 64) {
        if constexpr (FLAGS & FG_LNA) {
            const float4* xr = reinterpret_cast<const float4*>(
                Ax + (size_t)(row0 + arow_) * 256 + k0 + acq_ * 16);
            const float4* g4 = reinterpret_cast<const float4*>(lnS + k0 + acq_ * 16);
            const float4* b4 = reinterpret_cast<const float4*>(lnB + k0 + acq_ * 16);
            alignas(16) ushort tmp[16];
            #pragma unroll
            for (int u = 0; u < 4; ++u) {
                float4 xv = xr[u], gv = g4[u], bv = b4[u];
                tmp[u * 4 + 0] = f2b((xv.x - mean_) * rstd_ * gv.x + bv.x);
                tmp[u * 4 + 1] = f2b((xv.y - mean_) * rstd_ * gv.y + bv.y);
                tmp[u * 4 + 2] = f2b((xv.z - mean_) * rstd_ * gv.z + bv.z);
                tmp[u * 4 + 3] = f2b((xv.w - mean_) * rstd_ * gv.w + bv.w);
            }
            int c0 = acq_ * 2;
            *reinterpret_cast<uint4*>(As + arow_ * 64 + ((c0 ^ (arow_ & 7)) * 8)) =
                *reinterpret_cast<uint4*>(tmp);
            *reinterpret_cast<uint4*>(As + arow_ * 64 + (((c0 + 1) ^ (arow_ & 7)) * 8)) =
                *reinterpret_cast<uint4*>(tmp + 8);
        } else {
            #pragma unroll
            for (int c = 0; c < BM / 32; ++c) {
                int chunk = w * (BM / 32) + c;
                gload16(A + (size_t)(row0 + chunk * 8 + srow) * K + k0 + gcol,
                        As + chunk * 512);
            }
        }
        #pragma unroll
        for (int c = 0; c < BN / 32; ++c) {
            int chunk = w * (BN / 32) + c;
            gload16(Bt + (size_t)(col0 + chunk * 8 + srow) * K + k0 + gcol,
                    Bs + chunk * 512);
        }
        __syncthreads();
        #pragma unroll
        for (int kk = 0; kk < 2; ++kk) {
            bf16x8 a[WM], b[WN];
            #pragma unroll
            for (int m = 0; m < WM; ++m) {
                int rr = rA0 + m * 16;
                a[m] = *reinterpret_cast<const bf16x8*>(
                    As + rr * 64 + (((sl + kk * 4) ^ (rr & 7)) * 8));
            }
            #pragma unroll
            for (int n = 0; n < WN; ++n) {
                int rr = rB0 + n * 16;
                b[n] = *reinterpret_cast<const bf16x8*>(
                    Bs + rr * 64 + (((sl + kk * 4) ^ (rr & 7)) * 8));
            }
            #pragma unroll
            for (int m = 0; m < WM; ++m)
                #pragma unroll
                for (int n = 0; n < WN; ++n)
                    acc[m][n] = __builtin_amdgcn_mfma_f32_16x16x32_bf16(
                        a[m], b[n], acc[m][n], 0, 0, 0);
        }
        __syncthreads();
    }

    int lr = (lane >> 4) * 4;
    int lc = lane & 15;
    float psum[WM][4] = {};
    float psq[WM][4] = {};
    #pragma unroll
    for (int n = 0; n < WN; ++n) {
        int col = col0 + wc * (BN / 2) + n * 16 + lc;
        float bn = bias ? bias[col] : 0.f;
        float en = extra ? extra[col] : 0.f;
        #pragma unroll
        for (int m = 0; m < WM; ++m) {
            int rbase = row0 + wr * (BM / 2) + m * 16 + lr;
            #pragma unroll
            for (int r = 0; r < 4; ++r) {
                int row = rbase + r;
                float v = acc[m][n][r] + bn;
                if constexpr (FLAGS & FG_QKV) {
                    int which = col >> 8;
                    int c2 = col & 255;
                    int hh = c2 >> 6, dd = c2 & 63;
                    int bb = row >> 9, ss = row & 511;
                    if (which == 0) {
                        Cb[((((size_t)bb * NH_ + hh) * S_ + ss) << 6) + dd] =
                            f2b(v * 0.125f);
                    } else if (which == 1) {
                        (Cb + 1048576)[((((size_t)bb * NH_ + hh) * S_ + ss) << 6) + dd] =
                            f2b(v);
                    } else {
                        (Cb + 2097152)[((((size_t)bb * NH_ + hh) * HD_ + dd) << 9) + ss] =
                            f2b(v);
                    }
                } else {
                    if constexpr (FLAGS & FG_POS) v += pos[(size_t)(row & 511) * TN + col];
                    if (extra) v += en;
                    if (resid) v += resid[(size_t)row * TN + col];
                    if constexpr (FLAGS & FG_RELU) v = fmaxf(v, 0.f);
                    if constexpr (FLAGS & FG_STATS) {
                        psum[m][r] += v;
                        psq[m][r] += v * v;
                    }
                    if constexpr (FLAGS & FG_BF16)
                        Cb[(size_t)row * TN + col] = f2b(v);
                    if constexpr (FLAGS & FG_F32) {
                        if constexpr (FLAGS & FG_NT)
                            __builtin_nontemporal_store(v, &Cf[(size_t)row * TN + col]);
                        else
                            Cf[(size_t)row * TN + col] = v;
                    }
                }
            }
        }
    }
    if constexpr (FLAGS & FG_STATS) {
        int p = (col0 >> 6) * 2 + wc;
        #pragma unroll
        for (int m = 0; m < WM; ++m)
            #pragma unroll
            for (int r = 0; r < 4; ++r) {
                float s = psum[m][r], q2 = psq[m][r];
                #pragma unroll
                for (int o = 8; o > 0; o >>= 1) {
                    s  += __shfl_xor(s, o);
                    q2 += __shfl_xor(q2, o);
                }
                if (lc == 0) {
                    int row = row0 + wr * (BM / 2) + m * 16 + lr + r;
                    stats_out[p * 4096 + row] = make_float2(s, q2);
                }
            }
    }
}

// ---------------------------------------------------------------------------
// Fused flash attention: one block per (q-tile, bh).  4 waves x 16 q-rows.
// q,k head-major [bh][s][64] bf16 (q pre-scaled 1/8); v transposed [bh][d][s].
// ---------------------------------------------------------------------------
__global__ __launch_bounds__(256) void attn_kernel(
    const ushort* __restrict__ q, const ushort* __restrict__ k,
    const ushort* __restrict__ vT, ushort* __restrict__ pv)
{
    int qt = blockIdx.x, bh = blockIdx.y;
    __shared__ ushort Ks[64 * 64];
    __shared__ ushort Vs[64 * 64];
    __shared__ ushort Ps[4 * 16 * 64];
    int t = threadIdx.x, w = t >> 6, lane = t & 63;
    int srow = lane >> 3, slot = lane & 7;
    int gcol = (slot ^ srow) * 8;
    int sl = lane >> 4, lc = lane & 15;

    const ushort* Qp = q + ((size_t)bh * S_ + qt * 64) * HD_;
    const ushort* Kp = k + (size_t)bh * S_ * HD_;
    const ushort* Vp = vT + (size_t)bh * HD_ * S_;

    int qrow = w * 16 + lc;
    bf16x8 qf0 = *reinterpret_cast<const bf16x8*>(Qp + qrow * 64 + sl * 8);
    bf16x8 qf1 = *reinterpret_cast<const bf16x8*>(Qp + qrow * 64 + sl * 8 + 32);

    f32x4 o[4] = {};
    float m_r[4], l_r[4];
    #pragma unroll
    for (int r = 0; r < 4; ++r) { m_r[r] = -1e30f; l_r[r] = 0.f; }
    int row_abs = qt * 64 + w * 16 + sl * 4;

    for (int kt = 0; kt <= qt; ++kt) {
        #pragma unroll
        for (int c = 0; c < 2; ++c) {
            int chunk = w * 2 + c;
            gload16(Kp + (size_t)(kt * 64 + chunk * 8 + srow) * 64 + gcol,
                    Ks + chunk * 512);
            gload16(Vp + (size_t)(chunk * 8 + srow) * 512 + kt * 64 + gcol,
                    Vs + chunk * 512);
        }
        __syncthreads();

        f32x4 sa[4] = {};
        #pragma unroll
        for (int n = 0; n < 4; ++n) {
            int rB = n * 16 + lc;
            bf16x8 b0 = *reinterpret_cast<const bf16x8*>(
                Ks + rB * 64 + ((sl ^ (rB & 7)) * 8));
            bf16x8 b1 = *reinterpret_cast<const bf16x8*>(
                Ks + rB * 64 + (((sl + 4) ^ (rB & 7)) * 8));
            sa[n] = __builtin_amdgcn_mfma_f32_16x16x32_bf16(qf0, b0, sa[n], 0, 0, 0);
            sa[n] = __builtin_amdgcn_mfma_f32_16x16x32_bf16(qf1, b1, sa[n], 0, 0, 0);
        }
        if (kt == qt) {
            #pragma unroll
            for (int n = 0; n < 4; ++n) {
                int col = kt * 64 + n * 16 + lc;
                #pragma unroll
                for (int r = 0; r < 4; ++r)
                    if (col > row_abs + r) sa[n][r] = -1e30f;
            }
        }
        float psum[4];
        #pragma unroll
        for (int r = 0; r < 4; ++r) {
            float vm = fmaxf(fmaxf(sa[0][r], sa[1][r]), fmaxf(sa[2][r], sa[3][r]));
            vm = fmaxf(vm, __shfl_xor(vm, 1));
            vm = fmaxf(vm, __shfl_xor(vm, 2));
            vm = fmaxf(vm, __shfl_xor(vm, 4));
            vm = fmaxf(vm, __shfl_xor(vm, 8));
            float mn = fmaxf(m_r[r], vm);
            float scl = __expf(m_r[r] - mn);
            m_r[r] = mn;
            l_r[r] *= scl;
            #pragma unroll
            for (int n = 0; n < 4; ++n) o[n][r] *= scl;
            psum[r] = 0.f;
        }
        ushort* Pw = Ps + w * 1024;
        #pragma unroll
        for (int n = 0; n < 4; ++n) {
            #pragma unroll
            for (int r = 0; r < 4; ++r) {
                float p = __expf(sa[n][r] - m_r[r]);
                psum[r] += p;
                int prow = sl * 4 + r;
                int pcol = n * 16 + lc;
                int pslot = pcol >> 3;
                Pw[prow * 64 + ((pslot ^ (prow & 7)) * 8) + (pcol & 7)] = f2b(p);
            }
        }
        #pragma unroll
        for (int r = 0; r < 4; ++r) {
            float s = psum[r];
            s += __shfl_xor(s, 1);
            s += __shfl_xor(s, 2);
            s += __shfl_xor(s, 4);
            s += __shfl_xor(s, 8);
            l_r[r] += s;
        }
        int arow = lc;
        bf16x8 pa0 = *reinterpret_cast<const bf16x8*>(
            Pw + arow * 64 + ((sl ^ (arow & 7)) * 8));
        bf16x8 pa1 = *reinterpret_cast<const bf16x8*>(
            Pw + arow * 64 + (((sl + 4) ^ (arow & 7)) * 8));
        #pragma unroll
        for (int n = 0; n < 4; ++n) {
            int rB = n * 16 + lc;
            bf16x8 v0 = *reinterpret_cast<const bf16x8*>(
                Vs + rB * 64 + ((sl ^ (rB & 7)) * 8));
            bf16x8 v1 = *reinterpret_cast<const bf16x8*>(
                Vs + rB * 64 + (((sl + 4) ^ (rB & 7)) * 8));
            o[n] = __builtin_amdgcn_mfma_f32_16x16x32_bf16(pa0, v0, o[n], 0, 0, 0);
            o[n] = __builtin_amdgcn_mfma_f32_16x16x32_bf16(pa1, v1, o[n], 0, 0, 0);
        }
        __syncthreads();
    }

    int bb = bh >> 2, hh = bh & 3;
    #pragma unroll
    for (int r = 0; r < 4; ++r) {
        float inv = 1.f / l_r[r];
        int ss = qt * 64 + w * 16 + sl * 4 + r;
        #pragma unroll
        for (int n = 0; n < 4; ++n) {
            int dd = n * 16 + lc;
            pv[((size_t)bb * S_ + ss) * D_ + hh * HD_ + dd] = f2b(o[n][r] * inv);
        }
    }
}

// ===========================================================================
extern "C" void kernel_launch(void* const* d_in, const int* in_sizes, int n_in,
                              void* d_out, int out_size, void* d_ws, size_t ws_size,
                              hipStream_t stream)
{
    const int*   tok     = (const int*)  d_in[0];
    const float* ram     = (const float*)d_in[1];
    const float* proj_W  = (const float*)d_in[2];
    const float* proj_b  = (const float*)d_in[3];
    const float* pos_emb = (const float*)d_in[4];
    const float* sa_Wq   = (const float*)d_in[5];
    const float* sa_Wk   = (const float*)d_in[6];
    const float* sa_Wv   = (const float*)d_in[7];
    const float* sa_Wo   = (const float*)d_in[8];
    const float* sa_bq   = (const float*)d_in[9];
    const float* sa_bk   = (const float*)d_in[10];
    const float* sa_bv   = (const float*)d_in[11];
    const float* sa_bo   = (const float*)d_in[12];
    const float* ca_Wo   = (const float*)d_in[16];
    const float* ca_bv   = (const float*)d_in[19];
    const float* ca_bo   = (const float*)d_in[20];
    const float* ln1_s   = (const float*)d_in[21];
    const float* ln1_b   = (const float*)d_in[22];
    const float* ln3_s   = (const float*)d_in[25];
    const float* ln3_b   = (const float*)d_in[26];
    const float* ff_W1   = (const float*)d_in[27];
    const float* ff_b1   = (const float*)d_in[28];
    const float* ff_W2   = (const float*)d_in[29];
    const float* ff_b2   = (const float*)d_in[30];
    const float* out_W   = (const float*)d_in[31];
    const float* out_b   = (const float*)d_in[32];

    float* out = (float*)d_out;
    float* ws  = (float*)d_ws;

    // ws (must survive to logits): x | cc | xb | Wb
    float*  x   = ws;                            // BS_*D_ f32
    float*  cc  = ws + (size_t)BS_ * D_;         // L_*D_ f32
    ushort* xb  = (ushort*)(cc + L_ * D_);       // BS_*D_ bf16
    ushort* Wb  = xb + (size_t)BS_ * D_;         // V_*D_ bf16

    // d_out scratch (fully overwritten by the logits GEMM)
    ushort* sc_b  = (ushort*)out;                // 2,097,152
    ushort* qkv3  = sc_b + 2097152;              // 3,145,728 (q|k|vT)
    ushort* pv_b  = qkv3 + 3145728;              // 1,048,576
    ushort* ffh_b = pv_b + 1048576;              // 2,097,152
    ushort* pjWb  = ffh_b + 2097152;             // 131,072
    ushort* WqkvB = pjWb + 131072;               // 786,432  [L][768][256]
    ushort* WoB   = WqkvB + 786432;              // 262,144
    ushort* ff1B  = WoB + 262144;                // 524,288
    ushort* ff2B  = ff1B + 524288;               // 524,288
    float*  qkvb  = (float*)(ff2B + 524288);     // 4096 f32 (L*768 used)
    float2* stats = (float2*)(qkvb + 4096);      // 8*4096 float2
    ushort* qb_b  = qkv3;
    ushort* kb_b  = qkv3 + 1048576;
    ushort* vT_b  = qkv3 + 2097152;

    setup_kernel<<<L_, 1024, 0, stream>>>(ca_bv, ca_Wo, ca_bo, cc,
                                          sa_bq, sa_bk, sa_bv, qkvb);
    embed_bf16_kernel<<<BS_, 256, 0, stream>>>(tok, ram, sc_b);
    transpose_all_kernel<<<10176, dim3(32, 8), 0, stream>>>(
        proj_W, sa_Wq, sa_Wk, sa_Wv, sa_Wo, ff_W1, ff_W2, out_W,
        pjWb, WqkvB, WoB, ff1B, ff2B, Wb);

    // x = scores @ proj_W + proj_b + pos_emb  (+ row stats for ln1 of layer 0)
    gemm_t<64, 64, 512, 256, FG_F32 | FG_POS | FG_STATS><<<256, 256, 0, stream>>>(
        sc_b, nullptr, pjWb, proj_b, nullptr, nullptr, pos_emb,
        nullptr, nullptr, nullptr, stats, x, nullptr);

    for (int l = 0; l < L_; ++l) {
        // qkv = ln1(x) @ Wqkv + bqkv  (LN fused into A-staging)
        gemm_t<64, 64, 256, 768, FG_QKV | FG_LNA><<<768, 256, 0, stream>>>(
            nullptr, x, WqkvB + (size_t)l * 196608, qkvb + l * 768,
            nullptr, nullptr, nullptr, ln1_s + l * D_, ln1_b + l * D_,
            stats, nullptr, nullptr, qkv3);
        attn_kernel<<<dim3(8, 32), 256, 0, stream>>>(qb_b, kb_b, vT_b, pv_b);
        // x = x + pv @ Wo + bo + cc[l]  (+ stats for ln3)
        gemm_t<64, 64, 256, 256, FG_F32 | FG_STATS><<<256, 256, 0, stream>>>(
            pv_b, nullptr, WoB + (size_t)l * 65536, sa_bo + l * D_,
            cc + l * D_, x, nullptr, nullptr, nullptr, nullptr, stats, x, nullptr);
        // ffh = relu(ln3(x) @ W1 + b1)  (LN fused into A-staging)
        gemm_t<64, 64, 256, 512, FG_BF16 | FG_RELU | FG_LNA><<<512, 256, 0, stream>>>(
            nullptr, x, ff1B + (size_t)l * 131072, ff_b1 + l * FF_,
            nullptr, nullptr, nullptr, ln3_s + l * D_, ln3_b + l * D_,
            stats, nullptr, nullptr, ffh_b);
        if (l < L_ - 1) {
            // x = x + ffh @ W2 + b2  (+ stats for next layer's ln1)
            gemm_t<64, 64, 512, 256, FG_F32 | FG_STATS><<<256, 256, 0, stream>>>(
                ffh_b, nullptr, ff2B + (size_t)l * 131072, ff_b2 + l * D_,
                nullptr, x, nullptr, nullptr, nullptr, nullptr, stats, x, nullptr);
        } else {
            // last layer: emit x as bf16 directly for the logits GEMM
            gemm_t<64, 64, 512, 256, FG_BF16><<<256, 256, 0, stream>>>(
                ffh_b, nullptr, ff2B + (size_t)l * 131072, ff_b2 + l * D_,
                nullptr, x, nullptr, nullptr, nullptr, nullptr, nullptr,
                nullptr, xb);
        }
    }

    // logits = xb @ Wb^T + out_b  (overwrites all of d_out)
    gemm_t<128, 128, 256, 32000, FG_F32 | FG_NT><<<8000, 256, 0, stream>>>(
        xb, nullptr, Wb, out_b, nullptr, nullptr, nullptr,
        nullptr, nullptr, nullptr, nullptr, out, nullptr);
}

// Round 7
// 416.684 us; speedup vs baseline: 1.2113x; 1.2113x over previous
//
#include <hip/hip_runtime.h>

#define B_   8
#define S_   512
#define V_   32000
#define CTX_ 8
#define NC_  512
#define D_   256
#define NH_  4
#define L_   4
#define FF_  512
#define HD_  64
#define BS_  4096   // B_*S_

#define FG_F32   1   // write Cf f32 [row][TN]
#define FG_BF16  2   // write Cb bf16 [row][TN]
#define FG_RELU  4
#define FG_POS   8
#define FG_NT    16  // logits path: LDS-transposed float4 nontemporal stores
#define FG_QKV   32  // route to q/k/vT head layouts (TN=768)

typedef __attribute__((ext_vector_type(8))) short bf16x8;
typedef __attribute__((ext_vector_type(4))) float f32x4;

__device__ inline void gload16(const void* g, void* lds) {
    __builtin_amdgcn_global_load_lds(
        (const __attribute__((address_space(1))) void*)g,
        (__attribute__((address_space(3))) void*)lds, 16, 0, 0);
}

__device__ inline ushort f2b(float f) {   // f32 -> bf16 RNE
    union { float f; unsigned u; } v; v.f = f;
    unsigned u = v.u;
    unsigned r = u + 0x7fffu + ((u >> 16) & 1u);
    return (ushort)(r >> 16);
}

// ---------------------------------------------------------------------------
// Embedding: bf16 scores [BS][NC], pre-scaled by 1/8 (window mean)
// ---------------------------------------------------------------------------
__global__ __launch_bounds__(256) void embed_bf16_kernel(
    const int* __restrict__ tok, const float* __restrict__ table,
    ushort* __restrict__ scores)
{
    int bs = blockIdx.x;
    int b = bs >> 9, s = bs & 511;
    int j = threadIdx.x;
    float a0 = 0.f, a1 = 0.f;
    #pragma unroll
    for (int c = 0; c < CTX_; ++c) {
        int pos = s + c - (CTX_ - 1);
        int t = (pos < 0) ? 0 : tok[b * S_ + pos];
        const float* row = table + (size_t)t * NC_;
        a0 += row[j];
        a1 += row[j + 256];
    }
    scores[(size_t)bs * NC_ + j]       = f2b(a0 * 0.125f);
    scores[(size_t)bs * NC_ + j + 256] = f2b(a1 * 0.125f);
}

// ---------------------------------------------------------------------------
// LayerNorm f32 -> bf16, one WAVE per row (4 rows / 256-thread block)
// ---------------------------------------------------------------------------
__global__ __launch_bounds__(256) void ln_bf16_kernel(
    const float* __restrict__ x, const float* __restrict__ sc,
    const float* __restrict__ bi, ushort* __restrict__ out)
{
    int row = blockIdx.x * 4 + (threadIdx.x >> 6);
    int lane = threadIdx.x & 63;
    float4 v = *reinterpret_cast<const float4*>(x + (size_t)row * D_ + lane * 4);
    float s = v.x + v.y + v.z + v.w;
    float s2 = v.x * v.x + v.y * v.y + v.z * v.z + v.w * v.w;
    #pragma unroll
    for (int o = 32; o > 0; o >>= 1) {
        s  += __shfl_xor(s, o);
        s2 += __shfl_xor(s2, o);
    }
    float mean = s * (1.f / D_);
    float var = s2 * (1.f / D_) - mean * mean;
    float r = rsqrtf(var + 1e-5f);
    float4 g = *reinterpret_cast<const float4*>(sc + lane * 4);
    float4 bb = *reinterpret_cast<const float4*>(bi + lane * 4);
    ushort4 o4;
    o4.x = f2b((v.x - mean) * r * g.x + bb.x);
    o4.y = f2b((v.y - mean) * r * g.y + bb.y);
    o4.z = f2b((v.z - mean) * r * g.z + bb.z);
    o4.w = f2b((v.w - mean) * r * g.w + bb.w);
    *reinterpret_cast<ushort4*>(out + (size_t)row * D_ + lane * 4) = o4;
}

// ---------------------------------------------------------------------------
// Setup: cc[l] = ca_bv[l] @ ca_Wo[l] + ca_bo[l] (exact CA reduction)
//        qkvb[l][768] = concat(bq, bk, bv)
// ---------------------------------------------------------------------------
__global__ __launch_bounds__(1024) void setup_kernel(
    const float* __restrict__ ca_bv, const float* __restrict__ ca_Wo,
    const float* __restrict__ ca_bo, float* __restrict__ cc,
    const float* __restrict__ bq, const float* __restrict__ bk,
    const float* __restrict__ bv, float* __restrict__ qkvb)
{
    int l = blockIdx.x, t = threadIdx.x;
    if (t < 256) {
        const float* w = ca_Wo + (size_t)l * D_ * D_;
        const float* b = ca_bv + l * D_;
        float acc = 0.f;
        for (int d = 0; d < D_; ++d) acc += b[d] * w[(size_t)d * D_ + t];
        cc[l * D_ + t] = acc + ca_bo[l * D_ + t];
    } else {
        int u = t - 256;
        int which = u >> 8, c = u & 255;
        const float* src = which == 0 ? bq : which == 1 ? bk : bv;
        qkvb[l * 768 + u] = src[l * 256 + c];
    }
}

// ---------------------------------------------------------------------------
// All weight transposes in ONE launch: W[K][N] f32 -> Wb[N][K] bf16,
// 32x32 tiles, flat job id. Grid 10176, block (32,8).
// ---------------------------------------------------------------------------
__global__ void transpose_all_kernel(
    const float* __restrict__ proj_W, const float* __restrict__ Wq,
    const float* __restrict__ Wk, const float* __restrict__ Wv,
    const float* __restrict__ Wo, const float* __restrict__ W1,
    const float* __restrict__ W2, const float* __restrict__ outW,
    ushort* __restrict__ pjWb, ushort* __restrict__ WqkvB,
    ushort* __restrict__ WoB, ushort* __restrict__ ff1B,
    ushort* __restrict__ ff2B, ushort* __restrict__ Wb)
{
    int id = blockIdx.x;
    const float* src; ushort* dst; int K, N, lt;
    if (id < 128)       { src = proj_W; dst = pjWb; K = 512; N = 256; lt = id; }
    else if (id < 896)  { lt = id - 128; int z = lt >> 6; lt &= 63;
                          int which = z / L_, l = z % L_;
                          src = (which == 0 ? Wq : which == 1 ? Wk : Wv) + (size_t)l * 65536;
                          dst = WqkvB + ((size_t)l * 768 + which * 256) * 256;
                          K = 256; N = 256; }
    else if (id < 1152) { lt = id - 896; int l = lt >> 6; lt &= 63;
                          src = Wo + (size_t)l * 65536; dst = WoB + (size_t)l * 65536;
                          K = 256; N = 256; }
    else if (id < 1664) { lt = id - 1152; int l = lt >> 7; lt &= 127;
                          src = W1 + (size_t)l * 131072; dst = ff1B + (size_t)l * 131072;
                          K = 256; N = 512; }
    else if (id < 2176) { lt = id - 1664; int l = lt >> 7; lt &= 127;
                          src = W2 + (size_t)l * 131072; dst = ff2B + (size_t)l * 131072;
                          K = 512; N = 256; }
    else                { lt = id - 2176; src = outW; dst = Wb; K = 256; N = 32000; }
    int ntc = N >> 5;
    int n0 = (lt % ntc) * 32, k0 = (lt / ntc) * 32;
    __shared__ float tile[32][33];
    for (int i = threadIdx.y; i < 32; i += 8)
        tile[i][threadIdx.x] = src[(size_t)(k0 + i) * N + n0 + threadIdx.x];
    __syncthreads();
    for (int i = threadIdx.y; i < 32; i += 8)
        dst[(size_t)(n0 + i) * K + k0 + threadIdx.x] = f2b(tile[threadIdx.x][i]);
}

// ---------------------------------------------------------------------------
// Templated bf16 MFMA GEMM.  A[4096][K] bf16, Bt[TN][K] bf16.
// 4 waves (2x2).  BK=64.  LDS XOR-swizzled (T2, both-sides rule #21).
// FG_NT: epilogue stages C through LDS -> coalesced f32x4 nontemporal stores.
// ---------------------------------------------------------------------------
template<int BM, int BN, int K, int TN, int FLAGS>
__global__ __launch_bounds__(256) void gemm_t(
    const ushort* __restrict__ A, const ushort* __restrict__ Bt,
    const float* __restrict__ bias, const float* __restrict__ extra,
    const float* __restrict__ resid, const float* __restrict__ pos,
    float* __restrict__ Cf, ushort* __restrict__ Cb)
{
    constexpr int WM = BM / 32;
    constexpr int WN = BN / 32;
    constexpr int MT = 4096 / BM;
    constexpr int NWG = MT * (TN / BN);
    __shared__ ushort smem[(BM + BN) * 64];
    ushort* As = smem;
    ushort* Bs = smem + BM * 64;
    int bid = blockIdx.x;
    int swz = bid;
    if constexpr ((NWG & 7) == 0) {
        constexpr int cpx = NWG >> 3;
        swz = (bid & 7) * cpx + (bid >> 3);
    }
    int mt = swz % MT, nt = swz / MT;
    int row0 = mt * BM, col0 = nt * BN;
    int t = threadIdx.x, w = t >> 6, lane = t & 63;
    int wr = w >> 1, wc = w & 1;
    int srow = lane >> 3, slot = lane & 7;
    int gcol = (slot ^ srow) * 8;          // inverse-swizzled global col

    f32x4 acc[WM][WN] = {};
    int sl = lane >> 4;
    int rA0 = wr * (BM / 2) + (lane & 15);
    int rB0 = wc * (BN / 2) + (lane & 15);

    #pragma unroll
    for (int k0 = 0; k0 < K; k0 += 64) {
        #pragma unroll
        for (int c = 0; c < BM / 32; ++c) {
            int chunk = w * (BM / 32) + c;
            gload16(A + (size_t)(row0 + chunk * 8 + srow) * K + k0 + gcol,
                    As + chunk * 512);
        }
        #pragma unroll
        for (int c = 0; c < BN / 32; ++c) {
            int chunk = w * (BN / 32) + c;
            gload16(Bt + (size_t)(col0 + chunk * 8 + srow) * K + k0 + gcol,
                    Bs + chunk * 512);
        }
        __syncthreads();
        #pragma unroll
        for (int kk = 0; kk < 2; ++kk) {
            bf16x8 a[WM], b[WN];
            #pragma unroll
            for (int m = 0; m < WM; ++m) {
                int rr = rA0 + m * 16;
                a[m] = *reinterpret_cast<const bf16x8*>(
                    As + rr * 64 + (((sl + kk * 4) ^ (rr & 7)) * 8));
            }
            #pragma unroll
            for (int n = 0; n < WN; ++n) {
                int rr = rB0 + n * 16;
                b[n] = *reinterpret_cast<const bf16x8*>(
                    Bs + rr * 64 + (((sl + kk * 4) ^ (rr & 7)) * 8));
            }
            #pragma unroll
            for (int m = 0; m < WM; ++m)
                #pragma unroll
                for (int n = 0; n < WN; ++n)
                    acc[m][n] = __builtin_amdgcn_mfma_f32_16x16x32_bf16(
                        a[m], b[n], acc[m][n], 0, 0, 0);
        }
        __syncthreads();
    }

    int lr = (lane >> 4) * 4;
    int lc = lane & 15;

    if constexpr (FLAGS & FG_NT) {
        // C half-tile through LDS -> coalesced f32x4 nontemporal stores.
        float* Ct = reinterpret_cast<float*>(smem);   // (BM/2)*BN f32 == smem size
        #pragma unroll
        for (int p = 0; p < 2; ++p) {
            __syncthreads();
            if (wr == p) {
                #pragma unroll
                for (int n = 0; n < WN; ++n) {
                    int colL = wc * (BN / 2) + n * 16 + lc;
                    float bn = bias[col0 + colL];
                    #pragma unroll
                    for (int m = 0; m < WM; ++m)
                        #pragma unroll
                        for (int r = 0; r < 4; ++r)
                            Ct[(m * 16 + lr + r) * BN + colL] = acc[m][n][r] + bn;
                }
            }
            __syncthreads();
            constexpr int NV4 = (BM / 2) * (BN / 4);
            #pragma unroll
            for (int j = 0; j < NV4 / 256; ++j) {
                int idx = t + j * 256;
                int rl = idx / (BN / 4);
                int c4 = idx % (BN / 4);
                f32x4 v4 = reinterpret_cast<const f32x4*>(Ct)[idx];
                __builtin_nontemporal_store(v4,
                    reinterpret_cast<f32x4*>(
                        &Cf[(size_t)(row0 + p * (BM / 2) + rl) * TN + col0 + c4 * 4]));
            }
        }
        return;
    }

    #pragma unroll
    for (int n = 0; n < WN; ++n) {
        int col = col0 + wc * (BN / 2) + n * 16 + lc;
        float bn = bias ? bias[col] : 0.f;
        float en = extra ? extra[col] : 0.f;
        #pragma unroll
        for (int m = 0; m < WM; ++m) {
            int rbase = row0 + wr * (BM / 2) + m * 16 + lr;
            #pragma unroll
            for (int r = 0; r < 4; ++r) {
                int row = rbase + r;
                float v = acc[m][n][r] + bn;
                if constexpr (FLAGS & FG_QKV) {
                    int which = col >> 8;
                    int c2 = col & 255;
                    int hh = c2 >> 6, dd = c2 & 63;
                    int bb = row >> 9, ss = row & 511;
                    if (which == 0) {
                        Cb[((((size_t)bb * NH_ + hh) * S_ + ss) << 6) + dd] =
                            f2b(v * 0.125f);
                    } else if (which == 1) {
                        (Cb + 1048576)[((((size_t)bb * NH_ + hh) * S_ + ss) << 6) + dd] =
                            f2b(v);
                    } else {
                        (Cb + 2097152)[((((size_t)bb * NH_ + hh) * HD_ + dd) << 9) + ss] =
                            f2b(v);
                    }
                } else {
                    if constexpr (FLAGS & FG_POS) v += pos[(size_t)(row & 511) * TN + col];
                    if (extra) v += en;
                    if (resid) v += resid[(size_t)row * TN + col];
                    if constexpr (FLAGS & FG_RELU) v = fmaxf(v, 0.f);
                    if constexpr (FLAGS & FG_BF16)
                        Cb[(size_t)row * TN + col] = f2b(v);
                    if constexpr (FLAGS & FG_F32)
                        Cf[(size_t)row * TN + col] = v;
                }
            }
        }
    }
}

// ---------------------------------------------------------------------------
// Fused flash attention: one block per (q-tile, bh).  4 waves x 16 q-rows.
// q,k head-major [bh][s][64] bf16 (q pre-scaled 1/8); v transposed [bh][d][s].
// ---------------------------------------------------------------------------
__global__ __launch_bounds__(256) void attn_kernel(
    const ushort* __restrict__ q, const ushort* __restrict__ k,
    const ushort* __restrict__ vT, ushort* __restrict__ pv)
{
    int qt = blockIdx.x, bh = blockIdx.y;
    __shared__ ushort Ks[64 * 64];
    __shared__ ushort Vs[64 * 64];
    __shared__ ushort Ps[4 * 16 * 64];
    int t = threadIdx.x, w = t >> 6, lane = t & 63;
    int srow = lane >> 3, slot = lane & 7;
    int gcol = (slot ^ srow) * 8;
    int sl = lane >> 4, lc = lane & 15;

    const ushort* Qp = q + ((size_t)bh * S_ + qt * 64) * HD_;
    const ushort* Kp = k + (size_t)bh * S_ * HD_;
    const ushort* Vp = vT + (size_t)bh * HD_ * S_;

    int qrow = w * 16 + lc;
    bf16x8 qf0 = *reinterpret_cast<const bf16x8*>(Qp + qrow * 64 + sl * 8);
    bf16x8 qf1 = *reinterpret_cast<const bf16x8*>(Qp + qrow * 64 + sl * 8 + 32);

    f32x4 o[4] = {};
    float m_r[4], l_r[4];
    #pragma unroll
    for (int r = 0; r < 4; ++r) { m_r[r] = -1e30f; l_r[r] = 0.f; }
    int row_abs = qt * 64 + w * 16 + sl * 4;

    for (int kt = 0; kt <= qt; ++kt) {
        #pragma unroll
        for (int c = 0; c < 2; ++c) {
            int chunk = w * 2 + c;
            gload16(Kp + (size_t)(kt * 64 + chunk * 8 + srow) * 64 + gcol,
                    Ks + chunk * 512);
            gload16(Vp + (size_t)(chunk * 8 + srow) * 512 + kt * 64 + gcol,
                    Vs + chunk * 512);
        }
        __syncthreads();

        f32x4 sa[4] = {};
        #pragma unroll
        for (int n = 0; n < 4; ++n) {
            int rB = n * 16 + lc;
            bf16x8 b0 = *reinterpret_cast<const bf16x8*>(
                Ks + rB * 64 + ((sl ^ (rB & 7)) * 8));
            bf16x8 b1 = *reinterpret_cast<const bf16x8*>(
                Ks + rB * 64 + (((sl + 4) ^ (rB & 7)) * 8));
            sa[n] = __builtin_amdgcn_mfma_f32_16x16x32_bf16(qf0, b0, sa[n], 0, 0, 0);
            sa[n] = __builtin_amdgcn_mfma_f32_16x16x32_bf16(qf1, b1, sa[n], 0, 0, 0);
        }
        if (kt == qt) {
            #pragma unroll
            for (int n = 0; n < 4; ++n) {
                int col = kt * 64 + n * 16 + lc;
                #pragma unroll
                for (int r = 0; r < 4; ++r)
                    if (col > row_abs + r) sa[n][r] = -1e30f;
            }
        }
        float psum[4];
        #pragma unroll
        for (int r = 0; r < 4; ++r) {
            float vm = fmaxf(fmaxf(sa[0][r], sa[1][r]), fmaxf(sa[2][r], sa[3][r]));
            vm = fmaxf(vm, __shfl_xor(vm, 1));
            vm = fmaxf(vm, __shfl_xor(vm, 2));
            vm = fmaxf(vm, __shfl_xor(vm, 4));
            vm = fmaxf(vm, __shfl_xor(vm, 8));
            float mn = fmaxf(m_r[r], vm);
            float scl = __expf(m_r[r] - mn);
            m_r[r] = mn;
            l_r[r] *= scl;
            #pragma unroll
            for (int n = 0; n < 4; ++n) o[n][r] *= scl;
            psum[r] = 0.f;
        }
        ushort* Pw = Ps + w * 1024;
        #pragma unroll
        for (int n = 0; n < 4; ++n) {
            #pragma unroll
            for (int r = 0; r < 4; ++r) {
                float p = __expf(sa[n][r] - m_r[r]);
                psum[r] += p;
                int prow = sl * 4 + r;
                int pcol = n * 16 + lc;
                int pslot = pcol >> 3;
                Pw[prow * 64 + ((pslot ^ (prow & 7)) * 8) + (pcol & 7)] = f2b(p);
            }
        }
        #pragma unroll
        for (int r = 0; r < 4; ++r) {
            float s = psum[r];
            s += __shfl_xor(s, 1);
            s += __shfl_xor(s, 2);
            s += __shfl_xor(s, 4);
            s += __shfl_xor(s, 8);
            l_r[r] += s;
        }
        int arow = lc;
        bf16x8 pa0 = *reinterpret_cast<const bf16x8*>(
            Pw + arow * 64 + ((sl ^ (arow & 7)) * 8));
        bf16x8 pa1 = *reinterpret_cast<const bf16x8*>(
            Pw + arow * 64 + (((sl + 4) ^ (arow & 7)) * 8));
        #pragma unroll
        for (int n = 0; n < 4; ++n) {
            int rB = n * 16 + lc;
            bf16x8 v0 = *reinterpret_cast<const bf16x8*>(
                Vs + rB * 64 + ((sl ^ (rB & 7)) * 8));
            bf16x8 v1 = *reinterpret_cast<const bf16x8*>(
                Vs + rB * 64 + (((sl + 4) ^ (rB & 7)) * 8));
            o[n] = __builtin_amdgcn_mfma_f32_16x16x32_bf16(pa0, v0, o[n], 0, 0, 0);
            o[n] = __builtin_amdgcn_mfma_f32_16x16x32_bf16(pa1, v1, o[n], 0, 0, 0);
        }
        __syncthreads();
    }

    int bb = bh >> 2, hh = bh & 3;
    #pragma unroll
    for (int r = 0; r < 4; ++r) {
        float inv = 1.f / l_r[r];
        int ss = qt * 64 + w * 16 + sl * 4 + r;
        #pragma unroll
        for (int n = 0; n < 4; ++n) {
            int dd = n * 16 + lc;
            pv[((size_t)bb * S_ + ss) * D_ + hh * HD_ + dd] = f2b(o[n][r] * inv);
        }
    }
}

// ===========================================================================
extern "C" void kernel_launch(void* const* d_in, const int* in_sizes, int n_in,
                              void* d_out, int out_size, void* d_ws, size_t ws_size,
                              hipStream_t stream)
{
    const int*   tok     = (const int*)  d_in[0];
    const float* ram     = (const float*)d_in[1];
    const float* proj_W  = (const float*)d_in[2];
    const float* proj_b  = (const float*)d_in[3];
    const float* pos_emb = (const float*)d_in[4];
    const float* sa_Wq   = (const float*)d_in[5];
    const float* sa_Wk   = (const float*)d_in[6];
    const float* sa_Wv   = (const float*)d_in[7];
    const float* sa_Wo   = (const float*)d_in[8];
    const float* sa_bq   = (const float*)d_in[9];
    const float* sa_bk   = (const float*)d_in[10];
    const float* sa_bv   = (const float*)d_in[11];
    const float* sa_bo   = (const float*)d_in[12];
    const float* ca_Wo   = (const float*)d_in[16];
    const float* ca_bv   = (const float*)d_in[19];
    const float* ca_bo   = (const float*)d_in[20];
    const float* ln1_s   = (const float*)d_in[21];
    const float* ln1_b   = (const float*)d_in[22];
    const float* ln3_s   = (const float*)d_in[25];
    const float* ln3_b   = (const float*)d_in[26];
    const float* ff_W1   = (const float*)d_in[27];
    const float* ff_b1   = (const float*)d_in[28];
    const float* ff_W2   = (const float*)d_in[29];
    const float* ff_b2   = (const float*)d_in[30];
    const float* out_W   = (const float*)d_in[31];
    const float* out_b   = (const float*)d_in[32];

    float* out = (float*)d_out;
    float* ws  = (float*)d_ws;

    // ws (must survive to logits): x | cc | xb | Wb
    float*  x   = ws;                            // BS_*D_ f32
    float*  cc  = ws + (size_t)BS_ * D_;         // L_*D_ f32
    ushort* xb  = (ushort*)(cc + L_ * D_);       // BS_*D_ bf16
    ushort* Wb  = xb + (size_t)BS_ * D_;         // V_*D_ bf16

    // d_out scratch (fully overwritten by the logits GEMM)
    ushort* sc_b  = (ushort*)out;                // 2,097,152
    ushort* h_b   = sc_b + 2097152;              // 1,048,576
    ushort* qkv3  = h_b + 1048576;               // 3,145,728 (q|k|vT)
    ushort* pv_b  = qkv3 + 3145728;              // 1,048,576
    ushort* ffh_b = pv_b + 1048576;              // 2,097,152
    ushort* pjWb  = ffh_b + 2097152;             // 131,072
    ushort* WqkvB = pjWb + 131072;               // 786,432  [L][768][256]
    ushort* WoB   = WqkvB + 786432;              // 262,144
    ushort* ff1B  = WoB + 262144;                // 524,288
    ushort* ff2B  = ff1B + 524288;               // 524,288
    float*  qkvb  = (float*)(ff2B + 524288);     // 4096 f32 (L*768 used)
    ushort* qb_b  = qkv3;
    ushort* kb_b  = qkv3 + 1048576;
    ushort* vT_b  = qkv3 + 2097152;

    setup_kernel<<<L_, 1024, 0, stream>>>(ca_bv, ca_Wo, ca_bo, cc,
                                          sa_bq, sa_bk, sa_bv, qkvb);
    embed_bf16_kernel<<<BS_, 256, 0, stream>>>(tok, ram, sc_b);
    transpose_all_kernel<<<10176, dim3(32, 8), 0, stream>>>(
        proj_W, sa_Wq, sa_Wk, sa_Wv, sa_Wo, ff_W1, ff_W2, out_W,
        pjWb, WqkvB, WoB, ff1B, ff2B, Wb);

    // x = scores @ proj_W + proj_b + pos_emb
    gemm_t<64, 64, 512, 256, FG_F32 | FG_POS><<<256, 256, 0, stream>>>(
        sc_b, pjWb, proj_b, nullptr, nullptr, pos_emb, x, nullptr);

    for (int l = 0; l < L_; ++l) {
        ln_bf16_kernel<<<1024, 256, 0, stream>>>(x, ln1_s + l * D_, ln1_b + l * D_, h_b);
        gemm_t<64, 64, 256, 768, FG_QKV><<<768, 256, 0, stream>>>(
            h_b, WqkvB + (size_t)l * 196608, qkvb + l * 768,
            nullptr, nullptr, nullptr, nullptr, qkv3);
        attn_kernel<<<dim3(8, 32), 256, 0, stream>>>(qb_b, kb_b, vT_b, pv_b);
        // x = x + pv @ Wo + bo + cc[l]
        gemm_t<64, 64, 256, 256, FG_F32><<<256, 256, 0, stream>>>(
            pv_b, WoB + (size_t)l * 65536, sa_bo + l * D_,
            cc + l * D_, x, nullptr, x, nullptr);
        ln_bf16_kernel<<<1024, 256, 0, stream>>>(x, ln3_s + l * D_, ln3_b + l * D_, h_b);
        gemm_t<64, 64, 256, 512, FG_BF16 | FG_RELU><<<512, 256, 0, stream>>>(
            h_b, ff1B + (size_t)l * 131072, ff_b1 + l * FF_,
            nullptr, nullptr, nullptr, nullptr, ffh_b);
        if (l < L_ - 1) {
            gemm_t<64, 64, 512, 256, FG_F32><<<256, 256, 0, stream>>>(
                ffh_b, ff2B + (size_t)l * 131072, ff_b2 + l * D_,
                nullptr, x, nullptr, x, nullptr);
        } else {
            // last layer: emit x as bf16 directly for the logits GEMM
            gemm_t<64, 64, 512, 256, FG_BF16><<<256, 256, 0, stream>>>(
                ffh_b, ff2B + (size_t)l * 131072, ff_b2 + l * D_,
                nullptr, x, nullptr, nullptr, xb);
        }
    }

    // logits = xb @ Wb^T + out_b  (overwrites all of d_out)
    gemm_t<128, 128, 256, 32000, FG_F32 | FG_NT><<<8000, 256, 0, stream>>>(
        xb, Wb, out_b, nullptr, nullptr, nullptr, out, nullptr);
}